// Round 4
// baseline (385.122 us; speedup 1.0000x reference)
//
#include <hip/hip_runtime.h>
#include <hip/hip_bf16.h>

#define BATCH 8
#define CHN 256
#define HWN 16384
#define EPSV 1e-6f

typedef __attribute__((ext_vector_type(8))) short bf16x8;
typedef __attribute__((ext_vector_type(4))) float f32x4;
typedef __hip_bfloat16 bf16;

__device__ __forceinline__ void gload16(const bf16* g, bf16* l){
  __builtin_amdgcn_global_load_lds((const __attribute__((address_space(1))) void*)g,
                                   (__attribute__((address_space(3))) void*)l, 16, 0, 0);
}

// ---------------- K1: GroupNorm partial stats, 8 slices per (b,g) ------------
__global__ __launch_bounds__(256) void gn_stats(const float* __restrict__ x,
                                                float* __restrict__ pst){
  int blk = blockIdx.x;                      // 0..2047
  int bg = blk >> 3, sl = blk & 7;
  const float4* p4 = (const float4*)(x + (size_t)bg * (8 * HWN) + (size_t)sl * HWN);
  float s = 0.f, ss = 0.f;
  #pragma unroll 4
  for (int i = threadIdx.x; i < HWN / 4; i += 256){
    float4 v = p4[i];
    s  += v.x + v.y + v.z + v.w;
    ss += v.x*v.x + v.y*v.y + v.z*v.z + v.w*v.w;
  }
  __shared__ float rs[4], rss[4];
  for (int o = 32; o; o >>= 1){ s += __shfl_down(s, o); ss += __shfl_down(ss, o); }
  if ((threadIdx.x & 63) == 0){ rs[threadIdx.x >> 6] = s; rss[threadIdx.x >> 6] = ss; }
  __syncthreads();
  if (threadIdx.x == 0){
    atomicAdd(&pst[bg * 2],     rs[0]+rs[1]+rs[2]+rs[3]);
    atomicAdd(&pst[bg * 2 + 1], rss[0]+rss[1]+rss[2]+rss[3]);
  }
}

// ---------------- K2w: fp32 weights -> bf16 ----------------------------------
__global__ void wconv(const float* __restrict__ wq, const float* __restrict__ wk,
                      const float* __restrict__ wv, bf16* __restrict__ wb){
  int i = blockIdx.x * 256 + threadIdx.x;    // 0..65535
  int w = blockIdx.y;
  const float* src = (w == 0) ? wq : ((w == 1) ? wk : wv);
  wb[(size_t)w * 65536 + i] = __float2bfloat16(src[i]);
}

// ---------------- K2: normalize + transpose -> xnt[b][n][c] bf16 -------------
__global__ __launch_bounds__(256) void xnorm_t(const float* __restrict__ x,
    const float* __restrict__ pst,
    const float* __restrict__ gamma, const float* __restrict__ beta,
    bf16* __restrict__ xnt){
  int b = blockIdx.y, n0 = blockIdx.x * 64;
  __shared__ bf16 tile[256][70];
  int t = threadIdx.x;
  const float* xb = x + (size_t)b * CHN * HWN;
  #pragma unroll 4
  for (int i = 0; i < 16; i++){
    int c = i * 16 + (t >> 4);
    int nf = (t & 15) * 4;
    float4 v = *(const float4*)(xb + (size_t)c * HWN + n0 + nf);
    int bg = b * 32 + (c >> 3);
    float m   = pst[bg * 2] * (1.f / 131072.f);
    float var = pst[bg * 2 + 1] * (1.f / 131072.f) - m * m;
    float r = rsqrtf(var + EPSV);
    float a = r * gamma[c];
    float sh = beta[c] - m * a;
    tile[c][nf + 0] = __float2bfloat16(v.x * a + sh);
    tile[c][nf + 1] = __float2bfloat16(v.y * a + sh);
    tile[c][nf + 2] = __float2bfloat16(v.z * a + sh);
    tile[c][nf + 3] = __float2bfloat16(v.w * a + sh);
  }
  __syncthreads();
  bf16* o = xnt + (size_t)b * HWN * CHN;
  #pragma unroll 4
  for (int j = 0; j < 64; j++)
    o[(size_t)(n0 + j) * CHN + t] = tile[t][j];
}

// ---------------- K3: fused Q+K projection, E=exp epilogue, 2-phase ----------
// Block: all 512 weight rows (Wq 0-255, Wk 256-511) x 64 n-cols. 8 waves.
__global__ __launch_bounds__(512) void qk_gemm(const bf16* __restrict__ wqk,
    const bf16* __restrict__ xnt, bf16* __restrict__ Eout,
    float* __restrict__ sums){
  __shared__ bf16 lA[2][512 * 32];
  __shared__ bf16 lB[2][64 * 32];
  __shared__ float rsum[512];
  int t = threadIdx.x, nt = blockIdx.x, z = blockIdx.y;
  const bf16* Bt = xnt + (size_t)z * HWN * CHN + (size_t)(nt * 64) * CHN;
  rsum[t] = 0.f;
  f32x4 acc[4][4] = {};
  int lane = t & 63, w = t >> 6, r = lane & 15, kc = lane >> 4;

  auto stage = [&](int buf, int k0){
    #pragma unroll
    for (int rep = 0; rep < 4; rep++){
      int c = t + rep * 512; int row = c >> 2, off = (c & 3) * 8;
      gload16(wqk + (size_t)row * 256 + k0 + off, &lA[buf][c * 8]);
    }
    if (t < 256){
      int row = t >> 2, off = (t & 3) * 8;
      gload16(Bt + (size_t)row * 256 + k0 + off, &lB[buf][t * 8]);
    }
  };

  stage(0, 0);
  __syncthreads();
  int cur = 0;
  for (int ks = 0; ks < 8; ks++){
    if (ks < 7) stage(cur ^ 1, (ks + 1) * 32);
    bf16x8 af[4], bfv[4];
    #pragma unroll
    for (int f = 0; f < 4; f++){
      af[f]  = *(const bf16x8*)&lA[cur][(w * 64 + f * 16 + r) * 32 + kc * 8];
      bfv[f] = *(const bf16x8*)&lB[cur][(f * 16 + r) * 32 + kc * 8];
    }
    #pragma unroll
    for (int i = 0; i < 4; i++)
      #pragma unroll
      for (int j = 0; j < 4; j++)
        acc[i][j] = __builtin_amdgcn_mfma_f32_16x16x32_bf16(af[i], bfv[j], acc[i][j], 0, 0, 0);
    __syncthreads();
    cur ^= 1;
  }

  // epilogue: E = exp(acc), scattered store + per-row sums
  int colG0 = nt * 64 + r;
  int rowL0 = w * 64 + kc * 4;
  float colp[4][4];
  #pragma unroll
  for (int i = 0; i < 4; i++)
    #pragma unroll
    for (int j = 0; j < 4; j++) colp[i][j] = 0.f;

  #pragma unroll
  for (int i = 0; i < 4; i++){
    #pragma unroll
    for (int f = 0; f < 4; f++){
      int col = colG0 + f * 16;
      #pragma unroll
      for (int j = 0; j < 4; j++){
        int rowL = rowL0 + i * 16 + j;
        float e = __expf(acc[i][f][j]);      // |q| small: no max-sub needed
        size_t ridx = rowL < 256 ? (size_t)(z * 256 + rowL)
                                 : (size_t)(2048 + z * 256 + rowL - 256);
        Eout[ridx * HWN + col] = __float2bfloat16(e);
        colp[i][j] += e;
      }
    }
  }
  #pragma unroll
  for (int i = 0; i < 4; i++)
    #pragma unroll
    for (int j = 0; j < 4; j++){
      float v = colp[i][j];
      v += __shfl_xor(v, 1); v += __shfl_xor(v, 2);
      v += __shfl_xor(v, 4); v += __shfl_xor(v, 8);
      colp[i][j] = v;
    }
  if (r == 0){
    #pragma unroll
    for (int i = 0; i < 4; i++)
      #pragma unroll
      for (int j = 0; j < 4; j++)
        atomicAdd(&rsum[w * 64 + i * 16 + kc * 4 + j], colp[i][j]);
  }
  __syncthreads();
  size_t sidx = t < 256 ? (size_t)(z * 256 + t) : (size_t)(2048 + z * 256 + t - 256);
  atomicAdd(&sums[sidx], rsum[t]);
}

// ---------------- K4: V projection -> vt[b][n][d], xnt-stationary, 2-phase ---
__global__ __launch_bounds__(512) void v_gemm(const bf16* __restrict__ xnt,
    const bf16* __restrict__ wv, const float* __restrict__ bv,
    bf16* __restrict__ vt){
  __shared__ bf16 lA[2][128 * 32];
  __shared__ bf16 lB[2][256 * 32];
  int t = threadIdx.x, nt = blockIdx.x, z = blockIdx.y;
  const bf16* At = xnt + (size_t)z * HWN * CHN + (size_t)(nt * 128) * CHN;
  f32x4 acc[2][8] = {};
  int lane = t & 63, wid = t >> 6, r = lane & 15, kc = lane >> 4;
  int nw = wid & 3, dw = wid >> 2;

  auto stage = [&](int buf, int k0){
    { int row = t >> 2, off = (t & 3) * 8;
      gload16(At + (size_t)row * 256 + k0 + off, &lA[buf][t * 8]); }
    #pragma unroll
    for (int rep = 0; rep < 2; rep++){
      int c = t + rep * 512; int row = c >> 2, off = (c & 3) * 8;
      gload16(wv + (size_t)row * 256 + k0 + off, &lB[buf][c * 8]);
    }
  };

  stage(0, 0);
  __syncthreads();
  int cur = 0;
  for (int ks = 0; ks < 8; ks++){
    if (ks < 7) stage(cur ^ 1, (ks + 1) * 32);
    bf16x8 af[2], bfv[8];
    #pragma unroll
    for (int i = 0; i < 2; i++)
      af[i] = *(const bf16x8*)&lA[cur][(nw * 32 + i * 16 + r) * 32 + kc * 8];
    #pragma unroll
    for (int f = 0; f < 8; f++)
      bfv[f] = *(const bf16x8*)&lB[cur][(dw * 128 + f * 16 + r) * 32 + kc * 8];
    #pragma unroll
    for (int i = 0; i < 2; i++)
      #pragma unroll
      for (int f = 0; f < 8; f++)
        acc[i][f] = __builtin_amdgcn_mfma_f32_16x16x32_bf16(af[i], bfv[f], acc[i][f], 0, 0, 0);
    __syncthreads();
    cur ^= 1;
  }

  bf16* vb = vt + (size_t)z * HWN * CHN;
  #pragma unroll
  for (int i = 0; i < 2; i++){
    #pragma unroll
    for (int f = 0; f < 8; f++){
      int d = dw * 128 + f * 16 + r;
      float bcol = bv[d];
      #pragma unroll
      for (int j = 0; j < 4; j++){
        int n = nt * 128 + nw * 32 + i * 16 + kc * 4 + j;
        vb[(size_t)n * 256 + d] = __float2bfloat16(acc[i][f][j] + bcol);
      }
    }
  }
}

// ---------------- K5: ES partials = E_Q * E_K^T, K-chunked, 2-phase ----------
__global__ __launch_bounds__(256) void es_gemm(const bf16* __restrict__ Eq,
    const bf16* __restrict__ Ek, float* __restrict__ spart){
  __shared__ bf16 lA[2][128 * 32];
  __shared__ bf16 lB[2][128 * 32];
  int t = threadIdx.x, nt = blockIdx.x, mt = blockIdx.y, z = blockIdx.z;
  int b = z >> 3, ch = z & 7;
  const bf16* At = Eq + (size_t)b * CHN * HWN + (size_t)(mt * 128) * HWN + ch * 2048;
  const bf16* Bt = Ek + (size_t)b * CHN * HWN + (size_t)(nt * 128) * HWN + ch * 2048;
  f32x4 acc[4][4] = {};
  int lane = t & 63, wid = t >> 6, r = lane & 15, kc = lane >> 4;
  int wm = (wid >> 1) * 64, wn = (wid & 1) * 64;

  auto stage = [&](int buf, int k0){
    #pragma unroll
    for (int rep = 0; rep < 2; rep++){
      int c = t + rep * 256; int row = c >> 2, off = (c & 3) * 8;
      gload16(At + (size_t)row * HWN + k0 + off, &lA[buf][c * 8]);
      gload16(Bt + (size_t)row * HWN + k0 + off, &lB[buf][c * 8]);
    }
  };

  stage(0, 0);
  __syncthreads();
  int cur = 0;
  for (int ks = 0; ks < 64; ks++){
    if (ks < 63) stage(cur ^ 1, (ks + 1) * 32);
    bf16x8 af[4], bfv[4];
    #pragma unroll
    for (int f = 0; f < 4; f++){
      af[f]  = *(const bf16x8*)&lA[cur][(wm + f * 16 + r) * 32 + kc * 8];
      bfv[f] = *(const bf16x8*)&lB[cur][(wn + f * 16 + r) * 32 + kc * 8];
    }
    #pragma unroll
    for (int i = 0; i < 4; i++)
      #pragma unroll
      for (int j = 0; j < 4; j++)
        acc[i][j] = __builtin_amdgcn_mfma_f32_16x16x32_bf16(af[i], bfv[j], acc[i][j], 0, 0, 0);
    __syncthreads();
    cur ^= 1;
  }

  float* Ob = spart + (size_t)z * 65536;
  int colG0 = nt * 128 + wn + r;
  int rowG0 = mt * 128 + wm + kc * 4;
  #pragma unroll
  for (int i = 0; i < 4; i++)
    #pragma unroll
    for (int f = 0; f < 4; f++)
      #pragma unroll
      for (int j = 0; j < 4; j++)
        Ob[(size_t)(rowG0 + i * 16 + j) * 256 + colG0 + f * 16] = acc[i][f][j];
}

// ---------------- K6a: reduce K-chunk partials of ES --------------------------
__global__ void reduce_S(const float* __restrict__ sp, float* __restrict__ S){
  size_t i = (size_t)blockIdx.x * 256 + threadIdx.x;   // 8*65536 total
  size_t b = i >> 16, cd = i & 65535;
  float s = 0.f;
  #pragma unroll
  for (int ch = 0; ch < 8; ch++) s += sp[((b * 8 + ch) << 16) + cd];
  S[i] = s;
}

// ---------------- K6b: M = colscale(Wo,1/(16 sq)) * S, then /sk -> bf16 -------
__global__ __launch_bounds__(256) void make_M(const float* __restrict__ Wo,
    const float* __restrict__ S, const float* __restrict__ sq,
    const float* __restrict__ sk, bf16* __restrict__ Mb){
  int b = blockIdx.y, o0 = blockIdx.x * 16;
  __shared__ float wo_s[16][256];
  __shared__ float invsk[256];
  int t = threadIdx.x;
  #pragma unroll
  for (int i = 0; i < 16; i++){
    int idx = i * 256 + t, ol = idx >> 8, c = idx & 255;
    wo_s[ol][c] = Wo[(size_t)(o0 + ol) * 256 + c] * 0.0625f / sq[b * 256 + c];
  }
  invsk[t] = 1.f / sk[b * 256 + t];
  __syncthreads();
  int ol = t >> 4, d0 = (t & 15) * 16;
  const float* Sb = S + ((size_t)b << 16);
  float acc[16] = {};
  for (int c = 0; c < 256; c++){
    float w = wo_s[ol][c];
    const float4* Sr = (const float4*)(Sb + (c << 8) + d0);
    #pragma unroll
    for (int q4 = 0; q4 < 4; q4++){
      float4 sv = Sr[q4];
      acc[q4*4+0] += w * sv.x; acc[q4*4+1] += w * sv.y;
      acc[q4*4+2] += w * sv.z; acc[q4*4+3] += w * sv.w;
    }
  }
  bf16* Mo = Mb + ((size_t)b << 16) + (size_t)(o0 + ol) * 256 + d0;
  #pragma unroll
  for (int j = 0; j < 16; j++) Mo[j] = __float2bfloat16(acc[j] * invsk[d0 + j]);
}

// ---------------- K7: out = M * V^T + bo -> f32, vt-stationary, 2-phase ------
__global__ __launch_bounds__(512) void out_gemm(const bf16* __restrict__ Mb,
    const bf16* __restrict__ vt, const float* __restrict__ bo,
    float* __restrict__ out){
  __shared__ bf16 lA[2][256 * 32];
  __shared__ bf16 lB[2][128 * 32];
  int t = threadIdx.x, nt = blockIdx.x, z = blockIdx.y;
  const bf16* At = Mb + (size_t)z * 65536;
  const bf16* Bt = vt + (size_t)z * HWN * CHN + (size_t)(nt * 128) * CHN;
  f32x4 acc[8][2] = {};
  int lane = t & 63, wid = t >> 6, r = lane & 15, kc = lane >> 4;
  int ow = wid >> 2, nw = wid & 3;

  auto stage = [&](int buf, int k0){
    #pragma unroll
    for (int rep = 0; rep < 2; rep++){
      int c = t + rep * 512; int row = c >> 2, off = (c & 3) * 8;
      gload16(At + (size_t)row * 256 + k0 + off, &lA[buf][c * 8]);
    }
    { int row = t >> 2, off = (t & 3) * 8;
      gload16(Bt + (size_t)row * 256 + k0 + off, &lB[buf][t * 8]); }
  };

  stage(0, 0);
  __syncthreads();
  int cur = 0;
  for (int ks = 0; ks < 8; ks++){
    if (ks < 7) stage(cur ^ 1, (ks + 1) * 32);
    bf16x8 af[8], bfv[2];
    #pragma unroll
    for (int i = 0; i < 8; i++)
      af[i] = *(const bf16x8*)&lA[cur][(ow * 128 + i * 16 + r) * 32 + kc * 8];
    #pragma unroll
    for (int f = 0; f < 2; f++)
      bfv[f] = *(const bf16x8*)&lB[cur][(nw * 32 + f * 16 + r) * 32 + kc * 8];
    #pragma unroll
    for (int i = 0; i < 8; i++)
      #pragma unroll
      for (int f = 0; f < 2; f++)
        acc[i][f] = __builtin_amdgcn_mfma_f32_16x16x32_bf16(af[i], bfv[f], acc[i][f], 0, 0, 0);
    __syncthreads();
    cur ^= 1;
  }

  float* ob = out + (size_t)z * CHN * HWN;
  #pragma unroll
  for (int i = 0; i < 8; i++){
    #pragma unroll
    for (int j = 0; j < 4; j++){
      int o = ow * 128 + i * 16 + kc * 4 + j;
      float brow = bo[o];
      #pragma unroll
      for (int f = 0; f < 2; f++){
        int n = nt * 128 + nw * 32 + f * 16 + r;
        ob[(size_t)o * HWN + n] = acc[i][f][j] + brow;
      }
    }
  }
}

// ------------------------------------------------------------------------------
extern "C" void kernel_launch(void* const* d_in, const int* in_sizes, int n_in,
                              void* d_out, int out_size, void* d_ws, size_t ws_size,
                              hipStream_t stream){
  const float* x     = (const float*)d_in[0];
  const float* gamma = (const float*)d_in[1];
  const float* beta  = (const float*)d_in[2];
  const float* Wq    = (const float*)d_in[3];
  const float* Wk    = (const float*)d_in[5];
  const float* Wv    = (const float*)d_in[7];
  const float* bv    = (const float*)d_in[8];
  const float* Wo    = (const float*)d_in[9];
  const float* bo    = (const float*)d_in[10];
  // bq (d_in[4]) and bk (d_in[6]) are row-constant shifts -> cancel in softmax.

  char* ws = (char*)d_ws;
  bf16*  xnt   = (bf16*) (ws + 0);            // 64 MiB  xn^T [b][n][c]
  bf16*  vt    = (bf16*) (ws + 67108864);     // 64 MiB  V^T  [b][n][d]
  float* spart = (float*)(ws + 134217728);    // 16 MiB  ES partials [b*8+ch][c][d]
  float* S     = (float*)(ws + 150994944);    // 2 MiB   ES [b][c][d]
  bf16*  Mb    = (bf16*) (ws + 153092096);    // 1 MiB   M bf16 [b][o][d]
  bf16*  wb    = (bf16*) (ws + 154140672);    // 384 KiB Wq,Wk,Wv bf16
  float* sums  = (float*)(ws + 154533888);    // 16 KiB  sq[2048], sk[2048]
  float* pst   = (float*)(ws + 154550272);    // 2 KiB   GN partial s/ss per (b,g)

  bf16* Qb = (bf16*)d_out;                    // E_Q [b][o][n]; E_K follows

  hipMemsetAsync(sums, 0, 4096 * sizeof(float), stream);
  hipMemsetAsync(pst,  0,  512 * sizeof(float), stream);

  gn_stats<<<dim3(2048), dim3(256), 0, stream>>>(x, pst);
  wconv<<<dim3(256, 3), dim3(256), 0, stream>>>(Wq, Wk, Wv, wb);
  xnorm_t<<<dim3(256, 8), dim3(256), 0, stream>>>(x, pst, gamma, beta, xnt);

  // E_Q rows 0-255 (wb=Wq), E_K rows 256-511 (wb+64K=Wk); xnt read once.
  qk_gemm<<<dim3(256, 8), dim3(512), 0, stream>>>(wb, xnt, Qb, sums);

  // V^T[b][n][d] = xn^T * Wv^T + bv
  v_gemm<<<dim3(128, 8), dim3(512), 0, stream>>>(xnt, wb + 131072, bv, vt);

  // ES partials = E_Q * E_K^T over K-chunks of 2048
  es_gemm<<<dim3(2, 2, 64), dim3(256), 0, stream>>>(
      Qb, Qb + (size_t)BATCH * CHN * HWN, spart);
  reduce_S<<<dim3(2048), dim3(256), 0, stream>>>(spart, S);

  // M = (Wo . diag(1/(16 sq))) * ES * diag(1/sk)  -> bf16
  make_M<<<dim3(16, 8), dim3(256), 0, stream>>>(Wo, S, sums, sums + 2048, Mb);

  // out = M * V + bo  -> f32 [b][o][n]  (overwrites E scratch in d_out)
  out_gemm<<<dim3(128, 8), dim3(512), 0, stream>>>(Mb, vt, bo, (float*)d_out);
}

// Round 5
// 362.134 us; speedup vs baseline: 1.0635x; 1.0635x over previous
//
#include <hip/hip_runtime.h>
#include <hip/hip_bf16.h>

#define BATCH 8
#define CHN 256
#define HWN 16384
#define EPSV 1e-6f
#define ESCH 32

typedef __attribute__((ext_vector_type(8))) short bf16x8;
typedef __attribute__((ext_vector_type(4))) short s16x4;
typedef __attribute__((ext_vector_type(4))) float f32x4;
typedef __hip_bfloat16 bf16;

__device__ __forceinline__ short f2s(float f){
  union { bf16 h; short s; } u; u.h = __float2bfloat16(f); return u.s;
}
__device__ __forceinline__ void gload16(const bf16* g, bf16* l){
  __builtin_amdgcn_global_load_lds((const __attribute__((address_space(1))) void*)g,
                                   (__attribute__((address_space(3))) void*)l, 16, 0, 0);
}

// ---------------- K1: GroupNorm partial stats, 8 slices per (b,g) ------------
__global__ __launch_bounds__(256) void gn_stats(const float* __restrict__ x,
                                                float* __restrict__ pst){
  int blk = blockIdx.x;                      // 0..2047
  int bg = blk >> 3, sl = blk & 7;
  const float4* p4 = (const float4*)(x + (size_t)bg * (8 * HWN) + (size_t)sl * HWN);
  float s = 0.f, ss = 0.f;
  #pragma unroll 4
  for (int i = threadIdx.x; i < HWN / 4; i += 256){
    float4 v = p4[i];
    s  += v.x + v.y + v.z + v.w;
    ss += v.x*v.x + v.y*v.y + v.z*v.z + v.w*v.w;
  }
  __shared__ float rs[4], rss[4];
  for (int o = 32; o; o >>= 1){ s += __shfl_down(s, o); ss += __shfl_down(ss, o); }
  if ((threadIdx.x & 63) == 0){ rs[threadIdx.x >> 6] = s; rss[threadIdx.x >> 6] = ss; }
  __syncthreads();
  if (threadIdx.x == 0){
    atomicAdd(&pst[bg * 2],     rs[0]+rs[1]+rs[2]+rs[3]);
    atomicAdd(&pst[bg * 2 + 1], rss[0]+rss[1]+rss[2]+rss[3]);
  }
}

// ---------------- K2w: fp32 weights -> bf16 ----------------------------------
__global__ void wconv(const float* __restrict__ wq, const float* __restrict__ wk,
                      const float* __restrict__ wv, bf16* __restrict__ wb){
  int i = blockIdx.x * 256 + threadIdx.x;    // 0..65535
  int w = blockIdx.y;
  const float* src = (w == 0) ? wq : ((w == 1) ? wk : wv);
  wb[(size_t)w * 65536 + i] = __float2bfloat16(src[i]);
}

// ---------------- K2: normalize + transpose -> xnt[b][n][c] bf16 -------------
__global__ __launch_bounds__(256) void xnorm_t(const float* __restrict__ x,
    const float* __restrict__ pst,
    const float* __restrict__ gamma, const float* __restrict__ beta,
    bf16* __restrict__ xnt){
  int b = blockIdx.y, n0 = blockIdx.x * 64;
  __shared__ bf16 tile[256][70];
  int t = threadIdx.x;
  const float* xb = x + (size_t)b * CHN * HWN;
  #pragma unroll 4
  for (int i = 0; i < 16; i++){
    int c = i * 16 + (t >> 4);
    int nf = (t & 15) * 4;
    float4 v = *(const float4*)(xb + (size_t)c * HWN + n0 + nf);
    int bg = b * 32 + (c >> 3);
    float m   = pst[bg * 2] * (1.f / 131072.f);
    float var = pst[bg * 2 + 1] * (1.f / 131072.f) - m * m;
    float rr = rsqrtf(var + EPSV);
    float a = rr * gamma[c];
    float sh = beta[c] - m * a;
    tile[c][nf + 0] = __float2bfloat16(v.x * a + sh);
    tile[c][nf + 1] = __float2bfloat16(v.y * a + sh);
    tile[c][nf + 2] = __float2bfloat16(v.z * a + sh);
    tile[c][nf + 3] = __float2bfloat16(v.w * a + sh);
  }
  __syncthreads();
  bf16* o = xnt + (size_t)b * HWN * CHN;
  #pragma unroll 4
  for (int j = 0; j < 64; j++)
    o[(size_t)(n0 + j) * CHN + t] = tile[t][j];
}

// ---------------- K3: Q+K projection. A=xnt(n-side), B=Wqk(512 rows) ---------
// 256 thr / 4 waves; wave w owns wcols [w*128,+128); frags 4(n) x 8(w).
__global__ __launch_bounds__(256, 2) void qk_gemm(const bf16* __restrict__ wqk,
    const bf16* __restrict__ xnt, bf16* __restrict__ Eout,
    float* __restrict__ sums){
  __shared__ bf16 lB[2][512 * 32];           // 64 KB (weights)
  __shared__ bf16 lA[2][64 * 32];            // 8 KB (xnt tile)
  int t = threadIdx.x, nt = blockIdx.x, z = blockIdx.y;
  const bf16* At = xnt + (size_t)z * HWN * CHN + (size_t)(nt * 64) * CHN;
  f32x4 acc[4][8] = {};
  int lane = t & 63, w = t >> 6, r = lane & 15, kc = lane >> 4;

  auto stage = [&](int buf, int k0){
    #pragma unroll
    for (int rep = 0; rep < 8; rep++){
      int c = t + rep * 256; int row = c >> 2;
      int off = ((c & 3) ^ ((c >> 3) & 3)) * 8;          // pre-swizzled source
      gload16(wqk + (size_t)row * 256 + k0 + off, &lB[buf][c * 8]);
    }
    { int row = t >> 2;
      int off = ((t & 3) ^ ((t >> 3) & 3)) * 8;
      gload16(At + (size_t)row * 256 + k0 + off, &lA[buf][t * 8]); }
  };

  stage(0, 0);
  __syncthreads();
  int cur = 0;
  int slot8 = (kc ^ ((r >> 1) & 3)) * 8;                 // swizzled ds_read slot
  for (int ks = 0; ks < 8; ks++){
    if (ks < 7) stage(cur ^ 1, (ks + 1) * 32);
    bf16x8 af[4], bfv[8];
    #pragma unroll
    for (int i = 0; i < 4; i++)
      af[i] = *(const bf16x8*)&lA[cur][(i * 16 + r) * 32 + slot8];
    #pragma unroll
    for (int f = 0; f < 8; f++)
      bfv[f] = *(const bf16x8*)&lB[cur][(w * 128 + f * 16 + r) * 32 + slot8];
    #pragma unroll
    for (int i = 0; i < 4; i++)
      #pragma unroll
      for (int f = 0; f < 8; f++)
        acc[i][f] = __builtin_amdgcn_mfma_f32_16x16x32_bf16(af[i], bfv[f], acc[i][f], 0, 0, 0);
    __syncthreads();
    cur ^= 1;
  }

  // D[n][wrow]: lane holds 4 consecutive n at wrow = w*128+f*16+r.
  // E = exp(acc): pack 4 bf16 -> LDS scratch [512 wrow][64 n] (XOR bits[4:5] by wrow&3)
  bf16* scr = &lB[0][0];                                 // 64 KB reuse
  float colp[8];
  #pragma unroll
  for (int f = 0; f < 8; f++) colp[f] = 0.f;
  #pragma unroll
  for (int f = 0; f < 8; f++){
    int wrow = w * 128 + f * 16 + r;
    int key = (wrow & 3) << 4;
    char* rowp = (char*)scr + wrow * 128;
    #pragma unroll
    for (int i = 0; i < 4; i++){
      s16x4 pk;
      #pragma unroll
      for (int j = 0; j < 4; j++){
        float e = __expf(acc[i][f][j]);                  // |q| small: safe
        colp[f] += e;
        pk[j] = f2s(e);
      }
      *(s16x4*)(rowp + ((i * 32 + kc * 8) ^ key)) = pk;
    }
  }
  // row sums: lanes sharing wrow differ only in kc -> shfl 16,32
  #pragma unroll
  for (int f = 0; f < 8; f++){
    float v = colp[f];
    v += __shfl_xor(v, 16); v += __shfl_xor(v, 32);
    if (lane < 16){
      int wrow = w * 128 + f * 16 + r;
      size_t sidx = wrow < 256 ? (size_t)(z * 256 + wrow)
                               : (size_t)(2048 + z * 256 + wrow - 256);
      atomicAdd(&sums[sidx], v);
    }
  }
  __syncthreads();
  // coalesced store: per wave 8 rows x 128 B
  #pragma unroll
  for (int pass = 0; pass < 16; pass++){
    int c = t + pass * 256;
    int row = c >> 3, q = c & 7;
    int key = (row & 3) << 4;
    int4 v = *(const int4*)((const char*)scr + row * 128 + ((q * 16) ^ key));
    size_t ridx = row < 256 ? (size_t)(z * 256 + row)
                            : (size_t)(2048 + z * 256 + row - 256);
    *(int4*)&Eout[ridx * HWN + nt * 64 + q * 8] = v;
  }
}

// ---------------- K4: V projection -> vt[b][n][d]. A=xnt(128 n), B=Wv --------
__global__ __launch_bounds__(256, 2) void v_gemm(const bf16* __restrict__ xnt,
    const bf16* __restrict__ wv, const float* __restrict__ bv,
    bf16* __restrict__ vt){
  __shared__ char smem[65536];
  bf16* lA = (bf16*)smem;                    // [2][128*32] = 16 KB
  bf16* lB = (bf16*)(smem + 16384);          // [2][256*32] = 32 KB
  int t = threadIdx.x, nt = blockIdx.x, z = blockIdx.y;
  const bf16* At = xnt + (size_t)z * HWN * CHN + (size_t)(nt * 128) * CHN;
  f32x4 acc[4][8] = {};
  int lane = t & 63, w = t >> 6, r = lane & 15, kc = lane >> 4;
  int ng = w >> 1, cg = w & 1;

  auto stage = [&](int buf, int k0){
    #pragma unroll
    for (int rep = 0; rep < 2; rep++){
      int c = t + rep * 256; int row = c >> 2;
      int off = ((c & 3) ^ ((c >> 3) & 3)) * 8;
      gload16(At + (size_t)row * 256 + k0 + off, &lA[buf * 4096 + c * 8]);
    }
    #pragma unroll
    for (int rep = 0; rep < 4; rep++){
      int c = t + rep * 256; int row = c >> 2;
      int off = ((c & 3) ^ ((c >> 3) & 3)) * 8;
      gload16(wv + (size_t)row * 256 + k0 + off, &lB[buf * 8192 + c * 8]);
    }
  };

  stage(0, 0);
  __syncthreads();
  int cur = 0;
  int slot8 = (kc ^ ((r >> 1) & 3)) * 8;
  for (int ks = 0; ks < 8; ks++){
    if (ks < 7) stage(cur ^ 1, (ks + 1) * 32);
    bf16x8 af[4], bfv[8];
    #pragma unroll
    for (int i = 0; i < 4; i++)
      af[i] = *(const bf16x8*)&lA[cur * 4096 + (ng * 64 + i * 16 + r) * 32 + slot8];
    #pragma unroll
    for (int f = 0; f < 8; f++)
      bfv[f] = *(const bf16x8*)&lB[cur * 8192 + (cg * 128 + f * 16 + r) * 32 + slot8];
    #pragma unroll
    for (int i = 0; i < 4; i++)
      #pragma unroll
      for (int f = 0; f < 8; f++)
        acc[i][f] = __builtin_amdgcn_mfma_f32_16x16x32_bf16(af[i], bfv[f], acc[i][f], 0, 0, 0);
    __syncthreads();
    cur ^= 1;
  }

  // D[n][d] -> LDS scratch [128 n][256 d] (XOR bits[4:5] of d-offset by kc)
  bf16* scr = (bf16*)smem;
  #pragma unroll
  for (int f = 0; f < 8; f++){
    int d = cg * 128 + f * 16 + r;
    float bb = bv[d];
    #pragma unroll
    for (int i = 0; i < 4; i++)
      #pragma unroll
      for (int j = 0; j < 4; j++){
        int n = ng * 64 + i * 16 + kc * 4 + j;
        int key = ((n >> 2) & 3) << 4;
        *(short*)((char*)scr + n * 512 + ((d * 2) ^ key)) = f2s(acc[i][f][j] + bb);
      }
  }
  __syncthreads();
  bf16* vb = vt + (size_t)z * HWN * CHN + (size_t)(nt * 128) * CHN;
  #pragma unroll
  for (int pass = 0; pass < 16; pass++){
    int c = t + pass * 256;
    int row = c >> 5, q = c & 31;
    int key = ((row >> 2) & 3) << 4;
    int4 v = *(const int4*)((const char*)scr + row * 512 + ((q * 16) ^ key));
    *(int4*)&vb[(size_t)row * 256 + q * 8] = v;
  }
}

// ---------------- K5: ES split-K. A=E_K(128 rows), B=E_Q(256) ----------------
// D[kr][qr]: lane holds 4 consecutive kr -> float4 store to spart[q][k].
__global__ __launch_bounds__(256, 2) void es_gemm(const bf16* __restrict__ Ek,
    const bf16* __restrict__ Eq, float* __restrict__ spart){
  __shared__ bf16 lA[2][128 * 32];
  __shared__ bf16 lB[2][256 * 32];
  int t = threadIdx.x, ch = blockIdx.x, mt = blockIdx.y, z = blockIdx.z;
  const bf16* At = Ek + (size_t)z * 256 * HWN + (size_t)(mt * 128) * HWN + ch * 512;
  const bf16* Bt = Eq + (size_t)z * 256 * HWN + ch * 512;
  f32x4 acc[4][8] = {};
  int lane = t & 63, w = t >> 6, r = lane & 15, kc = lane >> 4;
  int ng = w >> 1, cg = w & 1;

  auto stage = [&](int buf, int k0){
    #pragma unroll
    for (int rep = 0; rep < 2; rep++){
      int c = t + rep * 256; int row = c >> 2;
      int off = ((c & 3) ^ ((c >> 3) & 3)) * 8;
      gload16(At + (size_t)row * HWN + k0 + off, &lA[buf][c * 8]);
    }
    #pragma unroll
    for (int rep = 0; rep < 4; rep++){
      int c = t + rep * 256; int row = c >> 2;
      int off = ((c & 3) ^ ((c >> 3) & 3)) * 8;
      gload16(Bt + (size_t)row * HWN + k0 + off, &lB[buf][c * 8]);
    }
  };

  stage(0, 0);
  __syncthreads();
  int cur = 0;
  int slot8 = (kc ^ ((r >> 1) & 3)) * 8;
  for (int ks = 0; ks < 16; ks++){
    if (ks < 15) stage(cur ^ 1, (ks + 1) * 32);
    bf16x8 af[4], bfv[8];
    #pragma unroll
    for (int i = 0; i < 4; i++)
      af[i] = *(const bf16x8*)&lA[cur][(ng * 64 + i * 16 + r) * 32 + slot8];
    #pragma unroll
    for (int f = 0; f < 8; f++)
      bfv[f] = *(const bf16x8*)&lB[cur][(cg * 128 + f * 16 + r) * 32 + slot8];
    #pragma unroll
    for (int i = 0; i < 4; i++)
      #pragma unroll
      for (int f = 0; f < 8; f++)
        acc[i][f] = __builtin_amdgcn_mfma_f32_16x16x32_bf16(af[i], bfv[f], acc[i][f], 0, 0, 0);
    __syncthreads();
    cur ^= 1;
  }

  float* sp = spart + ((size_t)(z * ESCH + ch) << 16);
  #pragma unroll
  for (int f = 0; f < 8; f++){
    int q = cg * 128 + f * 16 + r;
    #pragma unroll
    for (int i = 0; i < 4; i++){
      int k0i = mt * 128 + ng * 64 + i * 16 + kc * 4;
      *(f32x4*)&sp[q * 256 + k0i] = acc[i][f];
    }
  }
}

// ---------------- K6a: reduce split-K partials of ES --------------------------
__global__ void reduce_S(const float* __restrict__ sp, float* __restrict__ S){
  size_t i = (size_t)blockIdx.x * 256 + threadIdx.x;   // 8*65536 total
  size_t b = i >> 16, cd = i & 65535;
  float s = 0.f;
  #pragma unroll
  for (int ch = 0; ch < ESCH; ch++) s += sp[((b * ESCH + ch) << 16) + cd];
  S[i] = s;
}

// ---------------- K6b: M = colscale(Wo,1/(16 sq)) * S, then /sk -> bf16 -------
__global__ __launch_bounds__(256) void make_M(const float* __restrict__ Wo,
    const float* __restrict__ S, const float* __restrict__ sq,
    const float* __restrict__ sk, bf16* __restrict__ Mb){
  int b = blockIdx.y, o0 = blockIdx.x * 16;
  __shared__ float wo_s[16][256];
  __shared__ float invsk[256];
  int t = threadIdx.x;
  #pragma unroll
  for (int i = 0; i < 16; i++){
    int idx = i * 256 + t, ol = idx >> 8, c = idx & 255;
    wo_s[ol][c] = Wo[(size_t)(o0 + ol) * 256 + c] * 0.0625f / sq[b * 256 + c];
  }
  invsk[t] = 1.f / sk[b * 256 + t];
  __syncthreads();
  int ol = t >> 4, d0 = (t & 15) * 16;
  const float* Sb = S + ((size_t)b << 16);
  float acc[16] = {};
  for (int c = 0; c < 256; c++){
    float w = wo_s[ol][c];
    const float4* Sr = (const float4*)(Sb + (c << 8) + d0);
    #pragma unroll
    for (int q4 = 0; q4 < 4; q4++){
      float4 sv = Sr[q4];
      acc[q4*4+0] += w * sv.x; acc[q4*4+1] += w * sv.y;
      acc[q4*4+2] += w * sv.z; acc[q4*4+3] += w * sv.w;
    }
  }
  bf16* Mo = Mb + ((size_t)b << 16) + (size_t)(o0 + ol) * 256 + d0;
  #pragma unroll
  for (int j = 0; j < 16; j++) Mo[j] = __float2bfloat16(acc[j] * invsk[d0 + j]);
}

// ---------------- K7: out[o][n] = M*V^T + bo. A=vt(128 n), B=M(256 o) --------
// D[n][o]: lane holds 4 consecutive n -> direct float4 global store, no LDS.
__global__ __launch_bounds__(256, 2) void out_gemm(const bf16* __restrict__ vt,
    const bf16* __restrict__ Mb, const float* __restrict__ bo,
    float* __restrict__ out){
  __shared__ bf16 lA[2][128 * 32];
  __shared__ bf16 lB[2][256 * 32];
  int t = threadIdx.x, nt = blockIdx.x, z = blockIdx.y;
  const bf16* At = vt + (size_t)z * HWN * CHN + (size_t)(nt * 128) * CHN;
  const bf16* Bt = Mb + (size_t)z * 65536;
  f32x4 acc[4][8] = {};
  int lane = t & 63, w = t >> 6, r = lane & 15, kc = lane >> 4;
  int ng = w >> 1, cg = w & 1;

  auto stage = [&](int buf, int k0){
    #pragma unroll
    for (int rep = 0; rep < 2; rep++){
      int c = t + rep * 256; int row = c >> 2;
      int off = ((c & 3) ^ ((c >> 3) & 3)) * 8;
      gload16(At + (size_t)row * 256 + k0 + off, &lA[buf][c * 8]);
    }
    #pragma unroll
    for (int rep = 0; rep < 4; rep++){
      int c = t + rep * 256; int row = c >> 2;
      int off = ((c & 3) ^ ((c >> 3) & 3)) * 8;
      gload16(Bt + (size_t)row * 256 + k0 + off, &lB[buf][c * 8]);
    }
  };

  stage(0, 0);
  __syncthreads();
  int cur = 0;
  int slot8 = (kc ^ ((r >> 1) & 3)) * 8;
  for (int ks = 0; ks < 8; ks++){
    if (ks < 7) stage(cur ^ 1, (ks + 1) * 32);
    bf16x8 af[4], bfv[8];
    #pragma unroll
    for (int i = 0; i < 4; i++)
      af[i] = *(const bf16x8*)&lA[cur][(ng * 64 + i * 16 + r) * 32 + slot8];
    #pragma unroll
    for (int f = 0; f < 8; f++)
      bfv[f] = *(const bf16x8*)&lB[cur][(cg * 128 + f * 16 + r) * 32 + slot8];
    #pragma unroll
    for (int i = 0; i < 4; i++)
      #pragma unroll
      for (int f = 0; f < 8; f++)
        acc[i][f] = __builtin_amdgcn_mfma_f32_16x16x32_bf16(af[i], bfv[f], acc[i][f], 0, 0, 0);
    __syncthreads();
    cur ^= 1;
  }

  float* ob = out + (size_t)z * CHN * HWN;
  #pragma unroll
  for (int f = 0; f < 8; f++){
    int o = cg * 128 + f * 16 + r;
    float bb = bo[o];
    #pragma unroll
    for (int i = 0; i < 4; i++){
      int n0 = nt * 128 + ng * 64 + i * 16 + kc * 4;
      float4 st = { acc[i][f][0] + bb, acc[i][f][1] + bb,
                    acc[i][f][2] + bb, acc[i][f][3] + bb };
      *(float4*)&ob[(size_t)o * HWN + n0] = st;
    }
  }
}

// ------------------------------------------------------------------------------
extern "C" void kernel_launch(void* const* d_in, const int* in_sizes, int n_in,
                              void* d_out, int out_size, void* d_ws, size_t ws_size,
                              hipStream_t stream){
  const float* x     = (const float*)d_in[0];
  const float* gamma = (const float*)d_in[1];
  const float* beta  = (const float*)d_in[2];
  const float* Wq    = (const float*)d_in[3];
  const float* Wk    = (const float*)d_in[5];
  const float* Wv    = (const float*)d_in[7];
  const float* bv    = (const float*)d_in[8];
  const float* Wo    = (const float*)d_in[9];
  const float* bo    = (const float*)d_in[10];
  // bq (d_in[4]) and bk (d_in[6]) are row-constant shifts -> cancel in softmax.

  char* ws = (char*)d_ws;
  bf16*  xnt   = (bf16*) (ws + 0);            // 64 MiB  xn^T [b][n][c] (dead after v_gemm)
  float* spart = (float*)(ws + 0);            // 64 MiB  ES partials (overlays xnt)
  bf16*  vt    = (bf16*) (ws + 67108864);     // 64 MiB  V^T  [b][n][d]
  float* S     = (float*)(ws + 150994944);    // 2 MiB   ES [b][c][d]
  bf16*  Mb    = (bf16*) (ws + 153092096);    // 1 MiB   M bf16 [b][o][d]
  bf16*  wb    = (bf16*) (ws + 154140672);    // 384 KiB Wq,Wk,Wv bf16
  float* sums  = (float*)(ws + 154533888);    // 16 KiB  sq[2048], sk[2048]
  float* pst   = (float*)(ws + 154550272);    // 2 KiB   GN partial s/ss per (b,g)

  bf16* Qb = (bf16*)d_out;                    // E_Q [b][c][n]
  bf16* Kb = Qb + (size_t)2048 * HWN;         // E_K

  hipMemsetAsync(sums, 0, 4096 * sizeof(float), stream);
  hipMemsetAsync(pst,  0,  512 * sizeof(float), stream);

  gn_stats<<<dim3(2048), dim3(256), 0, stream>>>(x, pst);
  wconv<<<dim3(256, 3), dim3(256), 0, stream>>>(Wq, Wk, Wv, wb);
  xnorm_t<<<dim3(256, 8), dim3(256), 0, stream>>>(x, pst, gamma, beta, xnt);

  // E = exp(W_{q,k} xn) + row sums
  qk_gemm<<<dim3(256, 8), dim3(256), 0, stream>>>(wb, xnt, Qb, sums);
  // V^T[b][n][d]
  v_gemm<<<dim3(128, 8), dim3(256), 0, stream>>>(xnt, wb + 131072, bv, vt);
  // ES split-K partials (spart overlays dead xnt)
  es_gemm<<<dim3(ESCH, 2, 8), dim3(256), 0, stream>>>(Kb, Qb, spart);
  reduce_S<<<dim3(2048), dim3(256), 0, stream>>>(spart, S);
  // M = (Wo . diag(1/(16 sq))) * S * diag(1/sk) -> bf16
  make_M<<<dim3(16, 8), dim3(256), 0, stream>>>(Wo, S, sums, sums + 2048, Mb);
  // out = M * V + bo -> f32 (overwrites E scratch in d_out)
  out_gemm<<<dim3(128, 8), dim3(256), 0, stream>>>(vt, Mb, bo, (float*)d_out);
}